// Round 1
// baseline (311.292 us; speedup 1.0000x reference)
//
#include <hip/hip_runtime.h>

#define VOC 50257
#define EMB 128
#define NMEM 8192
#define TQ 50
#define TM 50
#define NHOPS 3

// ---------------- workspace layout (float offsets) ----------------
#define WS_U      0                        // 128
#define WS_MIN    (WS_U + EMB)             // 8192*128
#define WS_MOUT   (WS_MIN + NMEM*EMB)      // 8192*128
#define WS_D      (WS_MOUT + NMEM*EMB)     // 8192
#define WS_STATS  (WS_D + NMEM)            // 2 (max, sumexp)
#define WS_WPART  (WS_STATS + 2)           // 128*128
#define WS_LOGITS (WS_WPART + 128*EMB)     // 50257
#define WS_LSE    (WS_LOGITS + VOC)        // 1  (padding to even handled: WS_LOGITS even? not needed for f2 casts)

// u[e] = sum_t Wb[query[t]][e]
__global__ void k_u(const int* __restrict__ query, const float* __restrict__ Wb,
                    float* __restrict__ u) {
    int e = threadIdx.x;
    __shared__ int toks[TQ];
    if (e < TQ) toks[e] = query[e];
    __syncthreads();
    float acc = 0.f;
    for (int t = 0; t < TQ; ++t) acc += Wb[toks[t] * EMB + e];
    u[e] = acc;
}

// memory_in[n] = sum_t Wa[story[n,t]] + TA[n] ; memory_out analogous with Wc/TC
__global__ void k_mem(const int* __restrict__ story, const float* __restrict__ Wa,
                      const float* __restrict__ Wc, const float* __restrict__ TA,
                      const float* __restrict__ TC, float* __restrict__ min_,
                      float* __restrict__ mout) {
    int n = blockIdx.x;
    int e = threadIdx.x;
    __shared__ int toks[TM];
    if (e < TM) toks[e] = story[n * TM + e];
    __syncthreads();
    float a = TA[n * EMB + e];
    float c = TC[n * EMB + e];
    for (int t = 0; t < TM; ++t) {
        int off = toks[t] * EMB + e;
        a += Wa[off];
        c += Wc[off];
    }
    min_[n * EMB + e] = a;
    mout[n * EMB + e] = c;
}

// d[n] = dot(u, memory_in[n]) — one wave per row, 4 rows per 256-thread block
__global__ void k_dot(const float* __restrict__ min_, const float* __restrict__ u,
                      float* __restrict__ d) {
    int wave = threadIdx.x >> 6;
    int lane = threadIdx.x & 63;
    int n = blockIdx.x * 4 + wave;
    float2 uv = ((const float2*)u)[lane];
    float2 m = ((const float2*)(min_ + n * EMB))[lane];
    float p = uv.x * m.x + uv.y * m.y;
    #pragma unroll
    for (int o = 32; o > 0; o >>= 1) p += __shfl_xor(p, o);
    if (lane == 0) d[n] = p;
}

// softmax stats over 8192 scores: stats = {max, sum exp(d-max)}
__global__ void k_stats(const float* __restrict__ d, float* __restrict__ stats) {
    __shared__ float sm[256];
    int t = threadIdx.x;
    float m = -1e30f;
    for (int i = t; i < NMEM; i += 256) m = fmaxf(m, d[i]);
    sm[t] = m; __syncthreads();
    for (int s = 128; s > 0; s >>= 1) { if (t < s) sm[t] = fmaxf(sm[t], sm[t + s]); __syncthreads(); }
    float mx = sm[0]; __syncthreads();
    float s = 0.f;
    for (int i = t; i < NMEM; i += 256) s += __expf(d[i] - mx);
    sm[t] = s; __syncthreads();
    for (int st = 128; st > 0; st >>= 1) { if (t < st) sm[t] += sm[t + st]; __syncthreads(); }
    if (t == 0) { stats[0] = mx; stats[1] = sm[0]; }
}

// wpart[b][e] = sum over 64 rows of exp(d[n]-max) * memory_out[n][e]
__global__ void k_wpart(const float* __restrict__ mout, const float* __restrict__ d,
                        const float* __restrict__ stats, float* __restrict__ wpart) {
    int b = blockIdx.x;
    int e = threadIdx.x;
    __shared__ float w[64];
    float mx = stats[0];
    if (e < 64) w[e] = __expf(d[b * 64 + e] - mx);
    __syncthreads();
    float acc = 0.f;
    const float* base = mout + b * 64 * EMB + e;
    #pragma unroll 4
    for (int r = 0; r < 64; ++r) acc += w[r] * base[r * EMB];
    wpart[b * EMB + e] = acc;
}

// reduce partials -> weighted_out, then gated update of u
__global__ void k_update(const float* __restrict__ wpart, const float* __restrict__ stats,
                         const float* __restrict__ Wt_w, const float* __restrict__ Wt_b,
                         const float* __restrict__ H_w, const float* __restrict__ H_b,
                         float* __restrict__ u) {
    int e = threadIdx.x;
    __shared__ float wo[EMB], us[EMB];
    float inv = 1.f / stats[1];
    float acc = 0.f;
    for (int b = 0; b < 128; ++b) acc += wpart[b * EMB + e];
    wo[e] = acc * inv;
    us[e] = u[e];
    __syncthreads();
    float tg = Wt_b[e];
    float h = H_b[e];
    for (int k = 0; k < EMB; ++k) {
        tg += Wt_w[e * EMB + k] * us[k];
        h  += H_w[e * EMB + k] * wo[k];
    }
    float t = 1.f / (1.f + __expf(-tg));
    u[e] = us[e] * (1.f - t) + h * t;
}

// logits[v] = dot(u, weight_out[v]) — one wave per vocab row
__global__ void k_logits(const float* __restrict__ W, const float* __restrict__ u,
                         float* __restrict__ logits) {
    int wave = threadIdx.x >> 6;
    int lane = threadIdx.x & 63;
    int v = blockIdx.x * 4 + wave;
    if (v >= VOC) return;
    float2 uv = ((const float2*)u)[lane];
    float2 w = ((const float2*)(W + v * EMB))[lane];
    float p = uv.x * w.x + uv.y * w.y;
    #pragma unroll
    for (int o = 32; o > 0; o >>= 1) p += __shfl_xor(p, o);
    if (lane == 0) logits[v] = p;
}

// lse = max + log(sum exp(logits - max))
__global__ void k_lse(const float* __restrict__ logits, float* __restrict__ lse) {
    __shared__ float sm[1024];
    int t = threadIdx.x;
    float m = -1e30f;
    for (int i = t; i < VOC; i += 1024) m = fmaxf(m, logits[i]);
    sm[t] = m; __syncthreads();
    for (int s = 512; s > 0; s >>= 1) { if (t < s) sm[t] = fmaxf(sm[t], sm[t + s]); __syncthreads(); }
    float mx = sm[0]; __syncthreads();
    float s = 0.f;
    for (int i = t; i < VOC; i += 1024) s += __expf(logits[i] - mx);
    sm[t] = s; __syncthreads();
    for (int st = 512; st > 0; st >>= 1) { if (t < st) sm[t] += sm[t + st]; __syncthreads(); }
    if (t == 0) lse[0] = mx + __logf(sm[0]);
}

__global__ void k_out(const float* __restrict__ logits, const float* __restrict__ lse,
                      float* __restrict__ out) {
    int v = blockIdx.x * 256 + threadIdx.x;
    if (v < VOC) out[v] = logits[v] - lse[0];
}

extern "C" void kernel_launch(void* const* d_in, const int* in_sizes, int n_in,
                              void* d_out, int out_size, void* d_ws, size_t ws_size,
                              hipStream_t stream) {
    const int*   query = (const int*)d_in[0];
    const int*   story = (const int*)d_in[1];
    const float* Wa    = (const float*)d_in[2];
    const float* Wc    = (const float*)d_in[3];
    const float* Wb    = (const float*)d_in[4];
    const float* Wt_w  = (const float*)d_in[5];
    const float* Wt_b  = (const float*)d_in[6];
    const float* H_w   = (const float*)d_in[7];
    const float* H_b   = (const float*)d_in[8];
    const float* Wout  = (const float*)d_in[9];
    const float* TA    = (const float*)d_in[10];
    const float* TC    = (const float*)d_in[11];
    float* out = (float*)d_out;
    float* ws = (float*)d_ws;

    float* u      = ws + WS_U;
    float* min_   = ws + WS_MIN;
    float* mout   = ws + WS_MOUT;
    float* d      = ws + WS_D;
    float* stats  = ws + WS_STATS;
    float* wpart  = ws + WS_WPART;
    float* logits = ws + WS_LOGITS;
    float* lse    = ws + WS_LSE;

    k_u<<<1, EMB, 0, stream>>>(query, Wb, u);
    k_mem<<<NMEM, EMB, 0, stream>>>(story, Wa, Wc, TA, TC, min_, mout);

    for (int hop = 0; hop < NHOPS; ++hop) {
        k_dot<<<NMEM / 4, 256, 0, stream>>>(min_, u, d);
        k_stats<<<1, 256, 0, stream>>>(d, stats);
        k_wpart<<<128, EMB, 0, stream>>>(mout, d, stats, wpart);
        k_update<<<1, EMB, 0, stream>>>(wpart, stats, Wt_w, Wt_b, H_w, H_b, u);
    }

    k_logits<<<(VOC + 3) / 4, 256, 0, stream>>>(Wout, u, logits);
    k_lse<<<1, 1024, 0, stream>>>(logits, lse);
    k_out<<<(VOC + 255) / 256, 256, 0, stream>>>(logits, lse, out);
}

// Round 3
// 273.279 us; speedup vs baseline: 1.1391x; 1.1391x over previous
//
#include <hip/hip_runtime.h>

#define VOC 50257
#define EMB 128
#define NMEM 8192
#define TQ 50
#define TM 50
#define NHOPS 3

#define NDOT 256           // blocks in k_dot_stats
#define ROWS_PER_DOT (NMEM / NDOT)   // 32
#define NWP 128            // blocks in k_wpart
#define ROWS_PER_WP (NMEM / NWP)     // 64

// ---------------- workspace layout (float offsets) ----------------
#define WS_U      0
#define WS_MIN    (WS_U + EMB)
#define WS_MOUT   (WS_MIN + NMEM*EMB)
#define WS_D      (WS_MOUT + NMEM*EMB)
#define WS_BMAX   (WS_D + NMEM)
#define WS_BSUM   (WS_BMAX + NDOT)
#define WS_STATS  (WS_BSUM + NDOT)
#define WS_WPART  (WS_STATS + 4)
#define WS_LOGITS (WS_WPART + NWP*EMB)

// blocks 0..NMEM-1: memory_in/out build (8-way token-parallel float4 gathers)
// block NMEM: u[e] = sum_t Wb[query[t]][e]
__global__ void k_mem_u(const int* __restrict__ story, const int* __restrict__ query,
                        const float* __restrict__ Wa, const float* __restrict__ Wc,
                        const float* __restrict__ Wb, const float* __restrict__ TA,
                        const float* __restrict__ TC, float* __restrict__ min_,
                        float* __restrict__ mout, float* __restrict__ u) {
    int n = blockIdx.x;
    int t = threadIdx.x;
    if (n == NMEM) {
        __shared__ int q[TQ];
        if (t < TQ) q[t] = query[t];
        __syncthreads();
        if (t < EMB) {
            float acc = 0.f;
            for (int i = 0; i < TQ; ++i) acc += Wb[q[i] * EMB + t];
            u[t] = acc;
        }
        return;
    }
    __shared__ int toks[TM];
    __shared__ float smA[8 * EMB];
    __shared__ float smC[8 * EMB];
    if (t < TM) toks[t] = story[n * TM + t];
    __syncthreads();
    int g = t >> 5, l = t & 31;
    float4 a = {0.f, 0.f, 0.f, 0.f};
    float4 c = {0.f, 0.f, 0.f, 0.f};
    for (int tt = g; tt < TM; tt += 8) {
        const float4* pa = (const float4*)(Wa + toks[tt] * EMB);
        const float4* pc = (const float4*)(Wc + toks[tt] * EMB);
        float4 va = pa[l];
        float4 vc = pc[l];
        a.x += va.x; a.y += va.y; a.z += va.z; a.w += va.w;
        c.x += vc.x; c.y += vc.y; c.z += vc.z; c.w += vc.w;
    }
    ((float4*)smA)[g * 32 + l] = a;
    ((float4*)smC)[g * 32 + l] = c;
    __syncthreads();
    if (t < EMB) {
        float acc = TA[n * EMB + t];
        #pragma unroll
        for (int gg = 0; gg < 8; ++gg) acc += smA[gg * EMB + t];
        min_[n * EMB + t] = acc;
    } else {
        int e = t - EMB;
        float acc = TC[n * EMB + e];
        #pragma unroll
        for (int gg = 0; gg < 8; ++gg) acc += smC[gg * EMB + e];
        mout[n * EMB + e] = acc;
    }
}

// 256 blocks x 256 threads: d[n]=dot(u,min_[n]) for 32 rows/block (8 rows/wave),
// plus per-block softmax partials {max, sum exp(d-max)}.
__global__ void k_dot_stats(const float* __restrict__ min_, const float* __restrict__ u,
                            float* __restrict__ d, float* __restrict__ bmax,
                            float* __restrict__ bsum) {
    int b = blockIdx.x;
    int w = threadIdx.x >> 6, l = threadIdx.x & 63;
    __shared__ float2 su[64];
    __shared__ float ds[ROWS_PER_DOT];
    if (threadIdx.x < 64) su[threadIdx.x] = ((const float2*)u)[threadIdx.x];
    __syncthreads();
    float2 uv = su[l];
    #pragma unroll 2
    for (int r = 0; r < ROWS_PER_DOT / 4; ++r) {
        int rl = w * (ROWS_PER_DOT / 4) + r;
        int n = b * ROWS_PER_DOT + rl;
        float2 m = ((const float2*)(min_ + n * EMB))[l];
        float p = uv.x * m.x + uv.y * m.y;
        #pragma unroll
        for (int o = 32; o > 0; o >>= 1) p += __shfl_xor(p, o);
        if (l == 0) { ds[rl] = p; d[n] = p; }
    }
    __syncthreads();
    if (threadIdx.x < ROWS_PER_DOT) {
        float v = ds[threadIdx.x];
        float mx = v;
        #pragma unroll
        for (int o = 16; o > 0; o >>= 1) mx = fmaxf(mx, __shfl_xor(mx, o));
        float s = __expf(v - mx);
        #pragma unroll
        for (int o = 16; o > 0; o >>= 1) s += __shfl_xor(s, o);
        if (threadIdx.x == 0) { bmax[b] = mx; bsum[b] = s; }
    }
}

// 128 blocks x 128 threads: combine block stats into global {max,sum} (redundantly),
// then wpart[b][e] = sum_{r<64} exp(d[b*64+r]-gmax) * mout[b*64+r][e]  (unnormalized)
__global__ void k_wpart(const float* __restrict__ mout, const float* __restrict__ d,
                        const float* __restrict__ bmax, const float* __restrict__ bsum,
                        float* __restrict__ wpart, float* __restrict__ stats) {
    int b = blockIdx.x, t = threadIdx.x;
    __shared__ float w[ROWS_PER_WP];
    __shared__ float red[128];
    float m1 = fmaxf(bmax[t], bmax[t + 128]);
    red[t] = m1; __syncthreads();
    for (int s = 64; s > 0; s >>= 1) { if (t < s) red[t] = fmaxf(red[t], red[t + s]); __syncthreads(); }
    float gmax = red[0]; __syncthreads();
    float s1 = bsum[t] * __expf(bmax[t] - gmax) + bsum[t + 128] * __expf(bmax[t + 128] - gmax);
    red[t] = s1; __syncthreads();
    for (int s = 64; s > 0; s >>= 1) { if (t < s) red[t] += red[t + s]; __syncthreads(); }
    float gsum = red[0];
    if (b == 0 && t == 0) { stats[0] = gmax; stats[1] = gsum; }
    if (t < ROWS_PER_WP) w[t] = __expf(d[b * ROWS_PER_WP + t] - gmax);
    __syncthreads();
    float acc = 0.f;
    const float* base = mout + b * ROWS_PER_WP * EMB + t;
    #pragma unroll 4
    for (int r = 0; r < ROWS_PER_WP; ++r) acc += w[r] * base[r * EMB];
    wpart[b * EMB + t] = acc;
}

// 1 block x 128: weighted_out = (sum_b wpart[b]) / gsum, then gated update of u
__global__ void k_update(const float* __restrict__ wpart, const float* __restrict__ stats,
                         const float* __restrict__ Wt_w, const float* __restrict__ Wt_b,
                         const float* __restrict__ H_w, const float* __restrict__ H_b,
                         float* __restrict__ u) {
    int e = threadIdx.x;
    __shared__ float wo[EMB], us[EMB];
    float inv = 1.f / stats[1];
    float acc = 0.f;
    for (int b = 0; b < NWP; ++b) acc += wpart[b * EMB + e];
    wo[e] = acc * inv;
    us[e] = u[e];
    __syncthreads();
    float tg = Wt_b[e];
    float h = H_b[e];
    for (int k = 0; k < EMB; ++k) {
        tg += Wt_w[e * EMB + k] * us[k];
        h  += H_w[e * EMB + k] * wo[k];
    }
    float t = 1.f / (1.f + __expf(-tg));
    u[e] = us[e] * (1.f - t) + h * t;
}

// 8 vocab rows per 256-thread block: half-wave (32 lanes, float4) per row
__global__ void k_logits(const float* __restrict__ W, const float* __restrict__ u,
                         float* __restrict__ logits) {
    int w = threadIdx.x >> 6, l = threadIdx.x & 63;
    int half = l >> 5, l2 = l & 31;
    int v = blockIdx.x * 8 + w * 2 + half;
    __shared__ float4 su[32];
    if (threadIdx.x < 32) su[threadIdx.x] = ((const float4*)u)[threadIdx.x];
    __syncthreads();
    if (v >= VOC) return;
    float4 uv = su[l2];
    float4 wv = ((const float4*)(W + v * EMB))[l2];
    float p = uv.x * wv.x + uv.y * wv.y + uv.z * wv.z + uv.w * wv.w;
    #pragma unroll
    for (int o = 16; o > 0; o >>= 1) p += __shfl_xor(p, o);
    if (l2 == 0) logits[v] = p;
}

// single block: lse = max + log(sum exp(logits-max)); out = logits - lse
__global__ void k_lse_out(const float* __restrict__ logits, float* __restrict__ out) {
    __shared__ float sm[1024];
    int t = threadIdx.x;
    float m = -1e30f;
    for (int i = t; i < VOC; i += 1024) m = fmaxf(m, logits[i]);
    sm[t] = m; __syncthreads();
    for (int s = 512; s > 0; s >>= 1) { if (t < s) sm[t] = fmaxf(sm[t], sm[t + s]); __syncthreads(); }
    float mx = sm[0]; __syncthreads();
    float s = 0.f;
    for (int i = t; i < VOC; i += 1024) s += __expf(logits[i] - mx);
    sm[t] = s; __syncthreads();
    for (int st = 512; st > 0; st >>= 1) { if (t < st) sm[t] += sm[t + st]; __syncthreads(); }
    float lse = mx + __logf(sm[0]);
    for (int i = t; i < VOC; i += 1024) out[i] = logits[i] - lse;
}

extern "C" void kernel_launch(void* const* d_in, const int* in_sizes, int n_in,
                              void* d_out, int out_size, void* d_ws, size_t ws_size,
                              hipStream_t stream) {
    const int*   query = (const int*)d_in[0];
    const int*   story = (const int*)d_in[1];
    const float* Wa    = (const float*)d_in[2];
    const float* Wc    = (const float*)d_in[3];
    const float* Wb    = (const float*)d_in[4];
    const float* Wt_w  = (const float*)d_in[5];
    const float* Wt_b  = (const float*)d_in[6];
    const float* H_w   = (const float*)d_in[7];
    const float* H_b   = (const float*)d_in[8];
    const float* Wout  = (const float*)d_in[9];
    const float* TA    = (const float*)d_in[10];
    const float* TC    = (const float*)d_in[11];
    float* out = (float*)d_out;
    float* ws = (float*)d_ws;

    float* u      = ws + WS_U;
    float* min_   = ws + WS_MIN;
    float* mout   = ws + WS_MOUT;
    float* d      = ws + WS_D;
    float* bmax   = ws + WS_BMAX;
    float* bsum   = ws + WS_BSUM;
    float* stats  = ws + WS_STATS;
    float* wpart  = ws + WS_WPART;
    float* logits = ws + WS_LOGITS;

    k_mem_u<<<NMEM + 1, 256, 0, stream>>>(story, query, Wa, Wc, Wb, TA, TC, min_, mout, u);

    for (int hop = 0; hop < NHOPS; ++hop) {
        k_dot_stats<<<NDOT, 256, 0, stream>>>(min_, u, d, bmax, bsum);
        k_wpart<<<NWP, 128, 0, stream>>>(mout, d, bmax, bsum, wpart, stats);
        k_update<<<1, 128, 0, stream>>>(wpart, stats, Wt_w, Wt_b, H_w, H_b, u);
    }

    k_logits<<<(VOC + 7) / 8, 256, 0, stream>>>(Wout, u, logits);
    k_lse_out<<<1, 1024, 0, stream>>>(logits, out);
}